// Round 15
// baseline (347.777 us; speedup 1.0000x reference)
//
#include <hip/hip_runtime.h>
#include <hip/hip_bf16.h>
#include <math.h>
#include <stdint.h>

using bf16 = __hip_bfloat16;
typedef unsigned short u16;
typedef unsigned int   u32;
typedef __attribute__((ext_vector_type(8))) short short8;   // 8 bf16 bit patterns
typedef __attribute__((ext_vector_type(4))) float f32x4;
typedef _Float16 h2 __attribute__((ext_vector_type(2)));

static constexpr int NN   = 20000;
static constexpr int EE   = 320000;
static constexpr int ELN  = 100000;
static constexpr int ETOT = EE + NN;
static constexpr int INC  = 256;
static constexpr int C1   = 512;
static constexpr int C2   = 128;
static constexpr int NB   = (NN + 255) / 256;   // scan blocks = 79

__device__ __forceinline__ float us2f(u16 u){ union{u32 i; float f;}x; x.i=((u32)u)<<16; return x.f; }
__device__ __forceinline__ u16  f2us(float f){ union{bf16 h; u16 u;}c; c.h=__float2bfloat16(f); return c.u; }
__device__ __forceinline__ float h2f(u16 u){ union{u16 u; _Float16 h;}c; c.u=u; return (float)c.h; }
__device__ __forceinline__ float gelu_f(float x){
  float u = 1.5957691216057308f*(x + 0.044715f*x*x*x);
  float ex = __expf(u);
  float th = 1.f - 2.f/(ex + 1.f);
  return 0.5f*x*(1.f+th);
}
__device__ __forceinline__ void gl_lds16(const u16* g, void* l) {
  __builtin_amdgcn_global_load_lds((const __attribute__((address_space(1))) void*)g,
                                   (__attribute__((address_space(3))) void*)l, 16, 0, 0);
}
__device__ __forceinline__ void ld4v(const float* p, float* o){ float4 v=*(const float4*)p; o[0]=v.x;o[1]=v.y;o[2]=v.z;o[3]=v.w; }
__device__ __forceinline__ void ld4v(const u16* p, float* o){ uint2 v=*(const uint2*)p;
  o[0]=us2f(v.x&0xffff);o[1]=us2f(v.x>>16);o[2]=us2f(v.y&0xffff);o[3]=us2f(v.y>>16); }
__device__ __forceinline__ void ld4v(const _Float16* p, float* o){ uint2 v=*(const uint2*)p;
  o[0]=h2f(v.x&0xffff);o[1]=h2f(v.x>>16);o[2]=h2f(v.y&0xffff);o[3]=h2f(v.y>>16); }
__device__ __forceinline__ void ld8v(const float* p, float* o){ ld4v(p,o); ld4v(p+4,o+4); }
__device__ __forceinline__ void ld8v(const u16* p, float* o){ uint4 v=*(const uint4*)p;
  o[0]=us2f(v.x&0xffff);o[1]=us2f(v.x>>16);o[2]=us2f(v.y&0xffff);o[3]=us2f(v.y>>16);
  o[4]=us2f(v.z&0xffff);o[5]=us2f(v.z>>16);o[6]=us2f(v.w&0xffff);o[7]=us2f(v.w>>16); }
__device__ __forceinline__ void ld8v(const _Float16* p, float* o){ uint4 v=*(const uint4*)p;
  o[0]=h2f(v.x&0xffff);o[1]=h2f(v.x>>16);o[2]=h2f(v.y&0xffff);o[3]=h2f(v.y>>16);
  o[4]=h2f(v.z&0xffff);o[5]=h2f(v.z>>16);o[6]=h2f(v.w&0xffff);o[7]=h2f(v.w>>16); }
__device__ __forceinline__ void ld2v(const float* p, float* o){ float2 v=*(const float2*)p; o[0]=v.x;o[1]=v.y; }
__device__ __forceinline__ void ld2v(const _Float16* p, float* o){ u32 w=*(const u32*)p;
  o[0]=h2f(w&0xffff); o[1]=h2f(w>>16); }
__device__ __forceinline__ void st4v(float* p, const float* v){ *(float4*)p = make_float4(v[0],v[1],v[2],v[3]); }
__device__ __forceinline__ void st4v(u16* p, const float* v){ uint2 o;
  o.x=f2us(v[0])|((u32)f2us(v[1])<<16); o.y=f2us(v[2])|((u32)f2us(v[3])<<16); *(uint2*)p=o; }
__device__ __forceinline__ void st8v(float* p, const float* v){ st4v(p,v); st4v(p+4,v+4); }
__device__ __forceinline__ void st8v(u16* p, const float* v){ uint4 o;
  o.x=f2us(v[0])|((u32)f2us(v[1])<<16); o.y=f2us(v[2])|((u32)f2us(v[3])<<16);
  o.z=f2us(v[4])|((u32)f2us(v[5])<<16); o.w=f2us(v[6])|((u32)f2us(v[7])<<16); *(uint4*)p=o; }

// ---------------- fused preprocessing: xsplit + weight transpose/split + hist ----------------
struct PrepArgs {
  const float* x; u16* xth; u16* xtl; int nx;
  const float* wsrc[6]; u16* wth[6]; u16* wtl[6]; int wK[6]; int wN[6];
  const int* ei; int* cnt;
};
__global__ __launch_bounds__(256) void k_prep(PrepArgs a) {
  int seg = blockIdx.y;
  int tid = blockIdx.x*256 + threadIdx.x;
  int stride = gridDim.x*256;
  if (seg == 0) {
    for (int i = tid; i < a.nx; i += stride) {
      float v = a.x[i];
      u16 h = f2us(v);
      a.xth[i] = h;
      a.xtl[i] = f2us(v - us2f(h));
    }
  } else if (seg <= 6) {
    int s = seg - 1;
    int K = a.wK[s], N = a.wN[s];
    int n = K * N;
    for (int i = tid; i < n; i += stride) {
      int nn = i / K, k = i - nn*K;
      float v = a.wsrc[s][(size_t)k*N + nn];
      u16 h = f2us(v);
      a.wth[s][i] = h;
      a.wtl[s][i] = f2us(v - us2f(h));
    }
  } else {
    for (int e = tid; e < ETOT; e += stride) {
      int d = (e < EE) ? a.ei[EE + e] : (e - EE);
      if ((u32)d < (u32)NN) atomicAdd(&a.cnt[d], 1);
    }
  }
}

// ---------------- CSR scan/scatter ----------------
__global__ void k_scan_a(const int* __restrict__ cnt, int* __restrict__ row_ptr,
                         int* __restrict__ bsum) {
  __shared__ int buf[256];
  int idx = blockIdx.x*256 + threadIdx.x;
  int v = (idx < NN) ? cnt[idx] : 0;
  buf[threadIdx.x] = v;
  __syncthreads();
  for (int off = 1; off < 256; off <<= 1) {
    int t = (threadIdx.x >= off) ? buf[threadIdx.x - off] : 0;
    __syncthreads();
    buf[threadIdx.x] += t;
    __syncthreads();
  }
  if (idx < NN) row_ptr[idx] = buf[threadIdx.x] - v;
  if (threadIdx.x == 255) bsum[blockIdx.x] = buf[255];
}
__global__ void k_scan_b(int* __restrict__ bsum, int* __restrict__ row_ptr) {
  __shared__ int buf[128];
  int v = (threadIdx.x < NB) ? bsum[threadIdx.x] : 0;
  buf[threadIdx.x] = v;
  __syncthreads();
  for (int off = 1; off < 128; off <<= 1) {
    int t = (threadIdx.x >= off) ? buf[threadIdx.x - off] : 0;
    __syncthreads();
    buf[threadIdx.x] += t;
    __syncthreads();
  }
  if (threadIdx.x < NB) bsum[threadIdx.x] = buf[threadIdx.x] - v;
  if (threadIdx.x == 127) row_ptr[NN] = buf[127];
}
__global__ void k_scan_c(int* __restrict__ row_ptr, const int* __restrict__ bsum,
                         int* __restrict__ cur) {
  int idx = blockIdx.x*256 + threadIdx.x;
  if (idx < NN) {
    int v = row_ptr[idx] + bsum[blockIdx.x];
    row_ptr[idx] = v;
    cur[idx] = v;
  }
}
__global__ void k_scatter(const int* __restrict__ ei, int* __restrict__ cur,
                          int* __restrict__ col) {
  int e = blockIdx.x*blockDim.x + threadIdx.x;
  if (e < ETOT) {
    int s, d;
    if (e < EE) { s = ei[e]; d = ei[EE + e]; } else { s = d = e - EE; }
    if ((u32)d >= (u32)NN) d = 0;
    int pos = atomicAdd(&cur[d], 1);
    if ((u32)pos < (u32)ETOT) col[pos] = s;
  }
}

// ---------------- MFMA GEMM, async staging: C(fp16) = A @ B + bias ----------------
// biasB == nullptr means zero bias for cols >= ncut.
__global__ __launch_bounds__(256, 3)
void k_mgemm_a(const u16* __restrict__ Ath, const u16* __restrict__ Atl,
               const u16* __restrict__ Bth, const u16* __restrict__ Btl,
               const float* __restrict__ biasA, const float* __restrict__ biasB, int ncut,
               _Float16* __restrict__ C, int M, int N, int K, int nby) {
  __shared__ __align__(16) u16 sm[17408];
  int tid = threadIdx.x;
  int bidy = blockIdx.x % nby, bidx = blockIdx.x / nby;
  int m0 = bidx * 128, n0 = bidy * 128;
  int wave = tid >> 6, lane = tid & 63;
  int wm = (wave & 1) * 64, wn = (wave >> 1) * 64;
  int l15 = lane & 15, quad = lane >> 4;
  const u16* pbase = (wave == 0) ? Ath : (wave == 1) ? Atl : (wave == 2) ? Bth : Btl;
  bool isA = wave < 2;
  int rbase = isA ? m0 : n0;
  int rseg = lane >> 2;
  int kseg = (lane & 3) * 8;
  f32x4 acc[4][4] = {};
  for (int k0 = 0; k0 < K; k0 += 32) {
    #pragma unroll
    for (int i = 0; i < 8; ++i) {
      int r = rbase + i*16 + rseg;
      if (isA && r > M-1) r = M-1;
      gl_lds16(&pbase[(size_t)r*K + k0 + kseg], (char*)sm + (wave<<13) + (i<<10));
    }
    __syncthreads();
    short8 af_h[4], af_l[4], bf_h[4], bf_l[4];
    #pragma unroll
    for (int i = 0; i < 4; ++i) {
      af_h[i] = *(const short8*)&sm[         (wm + i*16 + l15)*32 + quad*8];
      af_l[i] = *(const short8*)&sm[ 4096 +  (wm + i*16 + l15)*32 + quad*8];
      bf_h[i] = *(const short8*)&sm[ 8192 +  (wn + i*16 + l15)*32 + quad*8];
      bf_l[i] = *(const short8*)&sm[12288 +  (wn + i*16 + l15)*32 + quad*8];
    }
    #pragma unroll
    for (int i = 0; i < 4; ++i)
      #pragma unroll
      for (int j = 0; j < 4; ++j) {
        acc[i][j] = __builtin_amdgcn_mfma_f32_16x16x32_bf16(af_h[i], bf_l[j], acc[i][j], 0,0,0);
        acc[i][j] = __builtin_amdgcn_mfma_f32_16x16x32_bf16(af_l[i], bf_h[j], acc[i][j], 0,0,0);
        acc[i][j] = __builtin_amdgcn_mfma_f32_16x16x32_bf16(af_h[i], bf_h[j], acc[i][j], 0,0,0);
      }
    __syncthreads();
  }
  #pragma unroll
  for (int j = 0; j < 4; ++j) {
    int col = wn + j*16 + l15;
    int colg = n0 + col;
    float bv = (colg < ncut) ? biasA[colg] : (biasB ? biasB[colg - ncut] : 0.f);
    #pragma unroll
    for (int i = 0; i < 4; ++i) {
      int rowb = wm + i*16 + quad*4;
      #pragma unroll
      for (int r = 0; r < 4; ++r) {
        union { _Float16 h; u16 u; } cv;
        cv.h = (_Float16)(acc[i][j][r] + bv);
        sm[(rowb + r)*136 + col] = cv.u;
      }
    }
  }
  __syncthreads();
  int row = tid >> 1, half = (tid & 1) * 64;
  int gr = m0 + row;
  if (gr < M) {
    uint4* d = (uint4*)&C[(size_t)gr*N + n0 + half];
    const uint4* s = (const uint4*)&sm[row*136 + half];
    #pragma unroll
    for (int q = 0; q < 8; ++q) d[q] = s[q];
  }
}

// ---------------- decoder epilogue: out[e] = Wd2 . gelu(UV[a][:128] + UV[b][128:]) + bd2
// UV[n] = [z2[n]@Wd1_top + bd1 | z2[n]@Wd1_bot]. One wave per edge, grid-stride.
__global__ __launch_bounds__(256) void k_dec5(const _Float16* __restrict__ UV,
                                              const int* __restrict__ eli,
                                              const float* __restrict__ Wd2,
                                              const float* __restrict__ bd2,
                                              float* __restrict__ out) {
  int gw = (blockIdx.x*256 + threadIdx.x) >> 6;
  int nw = (gridDim.x*256) >> 6;
  int lane = threadIdx.x & 63;
  int c2 = lane*2;
  float w2a = Wd2[c2], w2b = Wd2[c2+1];
  float b2 = bd2[0];
  for (int e = gw; e < ELN; e += nw) {
    int a = __builtin_amdgcn_readfirstlane(eli[e]);      if ((u32)a >= (u32)NN) a = 0;
    int b = __builtin_amdgcn_readfirstlane(eli[ELN+e]);  if ((u32)b >= (u32)NN) b = 0;
    float u[2], v[2];
    ld2v(&UV[(size_t)a*256 + c2], u);
    ld2v(&UV[(size_t)b*256 + 128 + c2], v);
    float p = gelu_f(u[0]+v[0])*w2a + gelu_f(u[1]+v[1])*w2b;
    p += __shfl_xor(p,1);  p += __shfl_xor(p,2);
    p += __shfl_xor(p,4);  p += __shfl_xor(p,8);
    p += __shfl_xor(p,16); p += __shfl_xor(p,32);
    if (lane == 0) out[e] = p + b2;
  }
}

// ---------------- edge layer 1: packed-fp16 math, 4-edge unroll ----------------
__global__ __launch_bounds__(256) void k_edge1p(const _Float16* __restrict__ xl,
                                                const _Float16* __restrict__ xr, int ld,
                                                const float* __restrict__ att,
                                                const float* __restrict__ bias,
                                                const int* __restrict__ row_ptr,
                                                const int* __restrict__ col,
                                                u16* __restrict__ z1h, u16* __restrict__ z1l) {
  int wid = (blockIdx.x*blockDim.x + threadIdx.x) >> 6;
  if (wid >= NN) return;
  int lane = threadIdx.x & 63;
  int c8 = lane*8;
  union Q { uint4 u; h2 h[4]; };
  Q XI; XI.u = *(const uint4*)&xr[(size_t)wid*ld + c8];
  h2 at[4];
  #pragma unroll
  for (int k=0;k<4;++k) { at[k][0] = (_Float16)att[c8+2*k]; at[k][1] = (_Float16)att[c8+2*k+1]; }
  const h2 k02 = {(_Float16)0.2f, (_Float16)0.2f};
  float acc[8] = {};
  float s = 0.f;
  int e0 = __builtin_amdgcn_readfirstlane(row_ptr[wid]);
  int e1 = __builtin_amdgcn_readfirstlane(row_ptr[wid+1]);
  int e = e0;
  for (; e + 4 <= e1; e += 4) {
    int s1 = __builtin_amdgcn_readfirstlane(col[e]);   if ((u32)s1 >= (u32)NN) s1 = 0;
    int s2 = __builtin_amdgcn_readfirstlane(col[e+1]); if ((u32)s2 >= (u32)NN) s2 = 0;
    int s3 = __builtin_amdgcn_readfirstlane(col[e+2]); if ((u32)s3 >= (u32)NN) s3 = 0;
    int s4 = __builtin_amdgcn_readfirstlane(col[e+3]); if ((u32)s4 >= (u32)NN) s4 = 0;
    Q X1, X2, X3, X4;
    X1.u = *(const uint4*)&xl[(size_t)s1*ld + c8];
    X2.u = *(const uint4*)&xl[(size_t)s2*ld + c8];
    X3.u = *(const uint4*)&xl[(size_t)s3*ld + c8];
    X4.u = *(const uint4*)&xl[(size_t)s4*ld + c8];
    float p1 = 0.f, p2 = 0.f, p3 = 0.f, p4 = 0.f;
    #pragma unroll
    for (int k=0;k<4;++k) {
      h2 t1 = XI.h[k] + X1.h[k]; t1 = __builtin_elementwise_max(t1, t1*k02);
      p1 = __builtin_amdgcn_fdot2(t1, at[k], p1, false);
      h2 t2 = XI.h[k] + X2.h[k]; t2 = __builtin_elementwise_max(t2, t2*k02);
      p2 = __builtin_amdgcn_fdot2(t2, at[k], p2, false);
      h2 t3 = XI.h[k] + X3.h[k]; t3 = __builtin_elementwise_max(t3, t3*k02);
      p3 = __builtin_amdgcn_fdot2(t3, at[k], p3, false);
      h2 t4 = XI.h[k] + X4.h[k]; t4 = __builtin_elementwise_max(t4, t4*k02);
      p4 = __builtin_amdgcn_fdot2(t4, at[k], p4, false);
    }
    p1 += __shfl_xor(p1,1); p2 += __shfl_xor(p2,1); p3 += __shfl_xor(p3,1); p4 += __shfl_xor(p4,1);
    p1 += __shfl_xor(p1,2); p2 += __shfl_xor(p2,2); p3 += __shfl_xor(p3,2); p4 += __shfl_xor(p4,2);
    p1 += __shfl_xor(p1,4); p2 += __shfl_xor(p2,4); p3 += __shfl_xor(p3,4); p4 += __shfl_xor(p4,4);
    p1 += __shfl_xor(p1,8); p2 += __shfl_xor(p2,8); p3 += __shfl_xor(p3,8); p4 += __shfl_xor(p4,8);
    float w1 = __expf(p1), w2 = __expf(p2), w3 = __expf(p3), w4 = __expf(p4);
    s += (w1 + w2) + (w3 + w4);
    #pragma unroll
    for (int k=0;k<4;++k) {
      acc[2*k]   += (w1*(float)X1.h[k][0] + w2*(float)X2.h[k][0])
                  + (w3*(float)X3.h[k][0] + w4*(float)X4.h[k][0]);
      acc[2*k+1] += (w1*(float)X1.h[k][1] + w2*(float)X2.h[k][1])
                  + (w3*(float)X3.h[k][1] + w4*(float)X4.h[k][1]);
    }
  }
  for (; e < e1; ++e) {
    int sn = __builtin_amdgcn_readfirstlane(col[e]); if ((u32)sn >= (u32)NN) sn = 0;
    Q XJ; XJ.u = *(const uint4*)&xl[(size_t)sn*ld + c8];
    float p = 0.f;
    #pragma unroll
    for (int k=0;k<4;++k) {
      h2 t = XI.h[k] + XJ.h[k];
      t = __builtin_elementwise_max(t, t*k02);
      p = __builtin_amdgcn_fdot2(t, at[k], p, false);
    }
    p += __shfl_xor(p,1); p += __shfl_xor(p,2);
    p += __shfl_xor(p,4); p += __shfl_xor(p,8);
    float w = __expf(p);
    s += w;
    #pragma unroll
    for (int k=0;k<4;++k) {
      acc[2*k]   += w*(float)XJ.h[k][0];
      acc[2*k+1] += w*(float)XJ.h[k][1];
    }
  }
  float inv = 1.f/s;
  u16 hh[8], ll[8];
  #pragma unroll
  for (int j=0;j<8;++j) {
    float o = gelu_f(acc[j]*inv + bias[c8+j]);
    hh[j] = f2us(o);
    ll[j] = f2us(o - us2f(hh[j]));
  }
  uint4 H, L;
  H.x = hh[0]|((u32)hh[1]<<16); H.y = hh[2]|((u32)hh[3]<<16);
  H.z = hh[4]|((u32)hh[5]<<16); H.w = hh[6]|((u32)hh[7]<<16);
  L.x = ll[0]|((u32)ll[1]<<16); L.y = ll[2]|((u32)ll[3]<<16);
  L.z = ll[4]|((u32)ll[5]<<16); L.w = ll[6]|((u32)ll[7]<<16);
  *(uint4*)&z1h[(size_t)wid*C1 + c8] = H;
  *(uint4*)&z1l[(size_t)wid*C1 + c8] = L;
}

// ---------------- edge layer 2: packed-fp16 math, 4-edge unroll, z2 bf16 hi/lo planes ----------------
__global__ __launch_bounds__(256) void k_edge2p(const _Float16* __restrict__ xl,
                                                const _Float16* __restrict__ xr, int ld,
                                                const float* __restrict__ att,
                                                const float* __restrict__ bias,
                                                const int* __restrict__ row_ptr,
                                                const int* __restrict__ col,
                                                u16* __restrict__ z2h, u16* __restrict__ z2l) {
  int wid = (blockIdx.x*blockDim.x + threadIdx.x) >> 6;
  if (wid >= NN) return;
  int lane = threadIdx.x & 63;
  int c2 = lane*2;
  union W { u32 u; h2 h; };
  W XI; XI.u = *(const u32*)&xr[(size_t)wid*ld + c2];
  h2 at; at[0] = (_Float16)att[c2]; at[1] = (_Float16)att[c2+1];
  const h2 k02 = {(_Float16)0.2f, (_Float16)0.2f};
  float s = 0.f, ac0 = 0.f, ac1 = 0.f;
  int e0 = __builtin_amdgcn_readfirstlane(row_ptr[wid]);
  int e1 = __builtin_amdgcn_readfirstlane(row_ptr[wid+1]);
  int e = e0;
  for (; e + 4 <= e1; e += 4) {
    int s1 = __builtin_amdgcn_readfirstlane(col[e]);   if ((u32)s1 >= (u32)NN) s1 = 0;
    int s2 = __builtin_amdgcn_readfirstlane(col[e+1]); if ((u32)s2 >= (u32)NN) s2 = 0;
    int s3 = __builtin_amdgcn_readfirstlane(col[e+2]); if ((u32)s3 >= (u32)NN) s3 = 0;
    int s4 = __builtin_amdgcn_readfirstlane(col[e+3]); if ((u32)s4 >= (u32)NN) s4 = 0;
    W X1, X2, X3, X4;
    X1.u = *(const u32*)&xl[(size_t)s1*ld + c2];
    X2.u = *(const u32*)&xl[(size_t)s2*ld + c2];
    X3.u = *(const u32*)&xl[(size_t)s3*ld + c2];
    X4.u = *(const u32*)&xl[(size_t)s4*ld + c2];
    h2 t1 = XI.h + X1.h; t1 = __builtin_elementwise_max(t1, t1*k02);
    h2 t2 = XI.h + X2.h; t2 = __builtin_elementwise_max(t2, t2*k02);
    h2 t3 = XI.h + X3.h; t3 = __builtin_elementwise_max(t3, t3*k02);
    h2 t4 = XI.h + X4.h; t4 = __builtin_elementwise_max(t4, t4*k02);
    float p1 = __builtin_amdgcn_fdot2(t1, at, 0.f, false);
    float p2 = __builtin_amdgcn_fdot2(t2, at, 0.f, false);
    float p3 = __builtin_amdgcn_fdot2(t3, at, 0.f, false);
    float p4 = __builtin_amdgcn_fdot2(t4, at, 0.f, false);
    p1 += __shfl_xor(p1,1);  p2 += __shfl_xor(p2,1);  p3 += __shfl_xor(p3,1);  p4 += __shfl_xor(p4,1);
    p1 += __shfl_xor(p1,2);  p2 += __shfl_xor(p2,2);  p3 += __shfl_xor(p3,2);  p4 += __shfl_xor(p4,2);
    p1 += __shfl_xor(p1,4);  p2 += __shfl_xor(p2,4);  p3 += __shfl_xor(p3,4);  p4 += __shfl_xor(p4,4);
    p1 += __shfl_xor(p1,8);  p2 += __shfl_xor(p2,8);  p3 += __shfl_xor(p3,8);  p4 += __shfl_xor(p4,8);
    p1 += __shfl_xor(p1,16); p2 += __shfl_xor(p2,16); p3 += __shfl_xor(p3,16); p4 += __shfl_xor(p4,16);
    p1 += __shfl_xor(p1,32); p2 += __shfl_xor(p2,32); p3 += __shfl_xor(p3,32); p4 += __shfl_xor(p4,32);
    float w1 = __expf(p1), w2 = __expf(p2), w3 = __expf(p3), w4 = __expf(p4);
    s += (w1 + w2) + (w3 + w4);
    ac0 += (w1*(float)X1.h[0] + w2*(float)X2.h[0]) + (w3*(float)X3.h[0] + w4*(float)X4.h[0]);
    ac1 += (w1*(float)X1.h[1] + w2*(float)X2.h[1]) + (w3*(float)X3.h[1] + w4*(float)X4.h[1]);
  }
  for (; e < e1; ++e) {
    int sn = __builtin_amdgcn_readfirstlane(col[e]); if ((u32)sn >= (u32)NN) sn = 0;
    W XJ; XJ.u = *(const u32*)&xl[(size_t)sn*ld + c2];
    h2 t = XI.h + XJ.h;
    t = __builtin_elementwise_max(t, t*k02);
    float p = __builtin_amdgcn_fdot2(t, at, 0.f, false);
    p += __shfl_xor(p,1);  p += __shfl_xor(p,2);
    p += __shfl_xor(p,4);  p += __shfl_xor(p,8);
    p += __shfl_xor(p,16); p += __shfl_xor(p,32);
    float w = __expf(p);
    s += w;
    ac0 += w*(float)XJ.h[0];
    ac1 += w*(float)XJ.h[1];
  }
  float inv = 1.f/s;
  float o0 = ac0*inv + bias[c2];
  float o1 = ac1*inv + bias[c2+1];
  u16 h0 = f2us(o0), h1 = f2us(o1);
  u16 l0 = f2us(o0 - us2f(h0)), l1v = f2us(o1 - us2f(h1));
  *(u32*)&z2h[(size_t)wid*C2 + c2] = h0 | ((u32)h1 << 16);
  *(u32*)&z2l[(size_t)wid*C2 + c2] = l0 | ((u32)l1v << 16);
}

// ================= compact-path fallback kernels =================
__global__ void k_hist(const int* __restrict__ ei, int* __restrict__ cnt) {
  int e = blockIdx.x*blockDim.x + threadIdx.x;
  if (e < ETOT) {
    int d = (e < EE) ? ei[EE + e] : (e - EE);
    if ((u32)d < (u32)NN) atomicAdd(&cnt[d], 1);
  }
}
template <typename AT, typename CT>
__global__ __launch_bounds__(256) void k_gemm(const AT* __restrict__ A,
                                              const float* __restrict__ W,
                                              const float* __restrict__ bias,
                                              CT* __restrict__ C,
                                              int M, int Nc, int K) {
  __shared__ __align__(16) float As[16][64];
  __shared__ __align__(16) float Bs[16][64];
  int tid = threadIdx.x;
  int m0 = blockIdx.x*64, n0 = blockIdx.y*64;
  int ty = tid >> 4, tx = tid & 15;
  int lrow = tid >> 2;
  int lk   = (tid & 3)*4;
  int wk   = tid >> 4;
  int wn   = (tid & 15)*4;
  float acc[4][4] = {};
  for (int k0 = 0; k0 < K; k0 += 16) {
    int row = m0 + lrow;
    if (row < M) {
      float a4[4]; ld4v(&A[(size_t)row*K + k0 + lk], a4);
      As[lk+0][lrow]=a4[0]; As[lk+1][lrow]=a4[1]; As[lk+2][lrow]=a4[2]; As[lk+3][lrow]=a4[3];
    } else {
      #pragma unroll
      for (int j=0;j<4;++j) As[lk+j][lrow]=0.f;
    }
    {
      float4 bv4 = *(const float4*)&W[(size_t)(k0+wk)*Nc + n0 + wn];
      Bs[wk][wn+0]=bv4.x; Bs[wk][wn+1]=bv4.y; Bs[wk][wn+2]=bv4.z; Bs[wk][wn+3]=bv4.w;
    }
    __syncthreads();
    #pragma unroll
    for (int kk=0;kk<16;++kk) {
      float4 av = *(const float4*)&As[kk][ty*4];
      float4 bv = *(const float4*)&Bs[kk][tx*4];
      float a[4]={av.x,av.y,av.z,av.w}, b[4]={bv.x,bv.y,bv.z,bv.w};
      #pragma unroll
      for (int i=0;i<4;++i)
        #pragma unroll
        for (int j=0;j<4;++j)
          acc[i][j] += a[i]*b[j];
    }
    __syncthreads();
  }
  float bv[4];
  #pragma unroll
  for (int j=0;j<4;++j) bv[j] = bias[n0 + tx*4 + j];
  #pragma unroll
  for (int i=0;i<4;++i) {
    int row = m0 + ty*4 + i;
    if (row < M) {
      float o4[4] = {acc[i][0]+bv[0], acc[i][1]+bv[1], acc[i][2]+bv[2], acc[i][3]+bv[3]};
      st4v(&C[(size_t)row*Nc + n0 + tx*4], o4);
    }
  }
}
template <typename TI, typename TO>
__global__ __launch_bounds__(256) void k_edge1c(const TI* __restrict__ xl,
                                                const TI* __restrict__ xr, int ld,
                                                const float* __restrict__ att,
                                                const float* __restrict__ bias,
                                                const int* __restrict__ row_ptr,
                                                const int* __restrict__ col,
                                                TO* __restrict__ z1) {
  int wid = (blockIdx.x*blockDim.x + threadIdx.x) >> 6;
  if (wid >= NN) return;
  int lane = threadIdx.x & 63;
  int c8 = lane*8;
  float xi[8], av[8], acc[8] = {};
  ld8v(&xr[(size_t)wid*ld + c8], xi);
  #pragma unroll
  for (int j=0;j<8;++j) av[j] = att[c8+j];
  float s = 0.f;
  int e0 = row_ptr[wid], e1 = row_ptr[wid+1];
  for (int e = e0; e < e1; ++e) {
    int sn = col[e]; if ((u32)sn >= (u32)NN) sn = 0;
    float xj[8];
    ld8v(&xl[(size_t)sn*ld + c8], xj);
    float p = 0.f;
    #pragma unroll
    for (int j=0;j<8;++j) {
      float t = xi[j] + xj[j];
      t = fmaxf(t, 0.2f*t);
      p += t*av[j];
    }
    p += __shfl_xor(p,1); p += __shfl_xor(p,2);
    p += __shfl_xor(p,4); p += __shfl_xor(p,8);
    float w = __expf(p);
    s += w;
    #pragma unroll
    for (int j=0;j<8;++j) acc[j] += w*xj[j];
  }
  float inv = 1.f/s, o[8];
  #pragma unroll
  for (int j=0;j<8;++j) o[j] = gelu_f(acc[j]*inv + bias[c8+j]);
  st8v(&z1[(size_t)wid*C1 + c8], o);
}
template <typename TI, typename TO>
__global__ __launch_bounds__(256) void k_edge2c(const TI* __restrict__ xl,
                                                const TI* __restrict__ xr, int ld,
                                                const float* __restrict__ att,
                                                const float* __restrict__ bias,
                                                const int* __restrict__ row_ptr,
                                                const int* __restrict__ col,
                                                TO* __restrict__ z2) {
  int wid = (blockIdx.x*blockDim.x + threadIdx.x) >> 6;
  if (wid >= NN) return;
  int lane = threadIdx.x & 63;
  int c2 = lane*2;
  float xiv[2];
  ld2v(&xr[(size_t)wid*ld + c2], xiv);
  float a0 = att[c2], a1 = att[c2+1];
  float s = 0.f, ac0 = 0.f, ac1 = 0.f;
  int e0 = row_ptr[wid], e1 = row_ptr[wid+1];
  for (int e = e0; e < e1; ++e) {
    int sn = col[e]; if ((u32)sn >= (u32)NN) sn = 0;
    float xj[2];
    ld2v(&xl[(size_t)sn*ld + c2], xj);
    float t0 = xiv[0] + xj[0]; t0 = fmaxf(t0, 0.2f*t0);
    float t1 = xiv[1] + xj[1]; t1 = fmaxf(t1, 0.2f*t1);
    float p = t0*a0 + t1*a1;
    p += __shfl_xor(p,1);  p += __shfl_xor(p,2);
    p += __shfl_xor(p,4);  p += __shfl_xor(p,8);
    p += __shfl_xor(p,16); p += __shfl_xor(p,32);
    float w = __expf(p);
    s += w;
    ac0 += w*xj[0];
    ac1 += w*xj[1];
  }
  float inv = 1.f/s;
  z2[(size_t)wid*C2 + c2]   = (TO)(ac0*inv + bias[c2]);
  z2[(size_t)wid*C2 + c2+1] = (TO)(ac1*inv + bias[c2+1]);
}
__global__ __launch_bounds__(256) void k_dec2(const float* __restrict__ z2,
                                              const int* __restrict__ eli,
                                              const float* __restrict__ Wd1,
                                              const float* __restrict__ bd1,
                                              const float* __restrict__ Wd2,
                                              const float* __restrict__ bd2,
                                              float* __restrict__ out) {
  __shared__ __align__(16) float As[16][64];
  __shared__ __align__(16) float Bs[16][128];
  int tid = threadIdx.x;
  int e0 = blockIdx.x * 64;
  int ty = tid >> 4, tx = tid & 15;
  int lrow = tid >> 2;
  int lk   = (tid & 3) * 4;
  int wk   = tid >> 4;
  int wn   = (tid & 15) * 8;
  int e = e0 + lrow;
  bool ev = e < ELN;
  int ia = ev ? eli[e] : 0;       if ((u32)ia >= (u32)NN) ia = 0;
  int ib = ev ? eli[ELN+e] : 0;   if ((u32)ib >= (u32)NN) ib = 0;
  float acc[4][8] = {};
  for (int k0 = 0; k0 < 256; k0 += 16) {
    int kk4 = k0 + lk;
    const float* src = (kk4 < 128) ? &z2[(size_t)ia*128 + kk4]
                                   : &z2[(size_t)ib*128 + (kk4 - 128)];
    float4 a4 = ev ? *(const float4*)src : make_float4(0.f,0.f,0.f,0.f);
    As[lk+0][lrow]=a4.x; As[lk+1][lrow]=a4.y; As[lk+2][lrow]=a4.z; As[lk+3][lrow]=a4.w;
    *(float4*)&Bs[wk][wn]   = *(const float4*)&Wd1[(size_t)(k0+wk)*128 + wn];
    *(float4*)&Bs[wk][wn+4] = *(const float4*)&Wd1[(size_t)(k0+wk)*128 + wn + 4];
    __syncthreads();
    #pragma unroll
    for (int kk = 0; kk < 16; ++kk) {
      float4 av = *(const float4*)&As[kk][ty*4];
      float a[4] = {av.x, av.y, av.z, av.w};
      float4 b0 = *(const float4*)&Bs[kk][tx*4];
      float4 b1 = *(const float4*)&Bs[kk][64 + tx*4];
      float b[8] = {b0.x,b0.y,b0.z,b0.w,b1.x,b1.y,b1.z,b1.w};
      #pragma unroll
      for (int i = 0; i < 4; ++i)
        #pragma unroll
        for (int j = 0; j < 8; ++j)
          acc[i][j] += a[i]*b[j];
    }
    __syncthreads();
  }
  float w2[8], bb[8];
  #pragma unroll
  for (int j = 0; j < 4; ++j) {
    w2[j]   = Wd2[tx*4+j];      bb[j]   = bd1[tx*4+j];
    w2[j+4] = Wd2[64+tx*4+j];   bb[j+4] = bd1[64+tx*4+j];
  }
  float b2 = bd2[0];
  #pragma unroll
  for (int i = 0; i < 4; ++i) {
    float part = 0.f;
    #pragma unroll
    for (int j = 0; j < 8; ++j)
      part += gelu_f(acc[i][j] + bb[j]) * w2[j];
    part += __shfl_xor(part,1); part += __shfl_xor(part,2);
    part += __shfl_xor(part,4); part += __shfl_xor(part,8);
    int row = e0 + ty*4 + i;
    if (tx == 0 && row < ELN) out[row] = part + b2;
  }
}

__global__ void k_tiny(float* out, float code) {
  if (threadIdx.x == 0) out[0] = code;
}

// ---------------- launch ----------------
extern "C" void kernel_launch(void* const* d_in, const int* in_sizes, int n_in,
                              void* d_out, int out_size, void* d_ws, size_t ws_size,
                              hipStream_t stream) {
  const float* x     = (const float*)d_in[0];
  const int*   ei    = (const int*)  d_in[1];
  const int*   eli   = (const int*)  d_in[2];
  const float* Wl1   = (const float*)d_in[3];
  const float* bl1   = (const float*)d_in[4];
  const float* Wr1   = (const float*)d_in[5];
  const float* br1   = (const float*)d_in[6];
  const float* att1  = (const float*)d_in[7];
  const float* bias1 = (const float*)d_in[8];
  const float* Wl2   = (const float*)d_in[9];
  const float* bl2   = (const float*)d_in[10];
  const float* Wr2   = (const float*)d_in[11];
  const float* br2   = (const float*)d_in[12];
  const float* att2  = (const float*)d_in[13];
  const float* bias2 = (const float*)d_in[14];
  const float* Wd1   = (const float*)d_in[15];
  const float* bd1   = (const float*)d_in[16];
  const float* Wd2   = (const float*)d_in[17];
  const float* bd2   = (const float*)d_in[18];
  float* out = (float*)d_out;

  constexpr size_t INTW = (size_t)(NN+1) + NN + ETOT;          // 380001 words
  constexpr size_t FULL_WORDS = 3ull*NN*C1 + INTW;             // ~124.4 MB (proven available)
  constexpr size_t CMP_WORDS  = 3ull*NN*C1/2 + INTW;           // ~63 MB

  bool full    = ws_size >= FULL_WORDS*4;
  bool compact = !full && ws_size >= CMP_WORDS*4;
  if (!full && !compact) {
    size_t mb = ws_size >> 20;
    k_tiny<<<1, 64, 0, stream>>>(out, 16384.f + (float)mb);
    return;
  }

  size_t regA = full ? (size_t)NN*C1 : (size_t)NN*C1/2;   // words per region
  char* base = (char*)d_ws;
  void* wA = base;
  void* wB = base + regA*4;
  void* wC = base + 2*regA*4;
  int* row_ptr = (int*)(base + 3*regA*4);
  int* cnt     = row_ptr + (NN + 1);
  int* col     = cnt + NN;
  int* bsum    = (int*)wA;   // scan scratch: wA dead during CSR phase

  hipMemsetAsync(cnt, 0, NN*sizeof(int), stream);

  if (full) {
    _Float16* xlr1 = (_Float16*)wA;
    _Float16* xlr2 = (_Float16*)wA;
    _Float16* UV   = (_Float16*)wA;               // [20000][256] fp16 (xlr2 dead after edge2)
    u16* xth = (u16*)wB;
    u16* xtl = xth + (size_t)NN*INC;
    u16* wt1th = (u16*)((char*)wB + (21u<<20));   // [1024][256]
    u16* wt1tl = wt1th + 1024*256;
    u16* wt2th = wt1tl + 1024*256;                // [256][512]
    u16* wt2tl = wt2th + 256*512;
    u16* wdth  = wt2tl + 256*512;                 // [256][128]  ([Wd1_top|Wd1_bot]^T)
    u16* wdtl  = wdth  + 256*128;
    u16* z1h = (u16*)wC;
    u16* z1l = z1h + (size_t)NN*C1;
    u16* z2h = (u16*)wC;                          // z1 planes dead after mgemm2
    u16* z2l = z2h + (size_t)NN*C2;

    // fused preprocessing: xsplit + 6 weight splits + hist in one dispatch
    PrepArgs pa;
    pa.x = x; pa.xth = xth; pa.xtl = xtl; pa.nx = NN*INC;
    pa.wsrc[0]=Wl1;          pa.wth[0]=wt1th;         pa.wtl[0]=wt1tl;         pa.wK[0]=INC; pa.wN[0]=C1;
    pa.wsrc[1]=Wr1;          pa.wth[1]=wt1th+512*256; pa.wtl[1]=wt1tl+512*256; pa.wK[1]=INC; pa.wN[1]=C1;
    pa.wsrc[2]=Wl2;          pa.wth[2]=wt2th;         pa.wtl[2]=wt2tl;         pa.wK[2]=C1;  pa.wN[2]=C2;
    pa.wsrc[3]=Wr2;          pa.wth[3]=wt2th+128*512; pa.wtl[3]=wt2tl+128*512; pa.wK[3]=C1;  pa.wN[3]=C2;
    pa.wsrc[4]=Wd1;          pa.wth[4]=wdth;          pa.wtl[4]=wdtl;          pa.wK[4]=128; pa.wN[4]=128;
    pa.wsrc[5]=Wd1+128*128;  pa.wth[5]=wdth+128*128;  pa.wtl[5]=wdtl+128*128;  pa.wK[5]=128; pa.wN[5]=128;
    pa.ei = ei; pa.cnt = cnt;
    k_prep<<<dim3(1344, 8), 256, 0, stream>>>(pa);

    k_scan_a<<<NB, 256, 0, stream>>>(cnt, row_ptr, bsum);
    k_scan_b<<<1, 128, 0, stream>>>(bsum, row_ptr);
    k_scan_c<<<NB, 256, 0, stream>>>(row_ptr, bsum, cnt);
    k_scatter<<<(ETOT+255)/256, 256, 0, stream>>>(ei, cnt, col);

    k_mgemm_a<<<157*8, 256, 0, stream>>>(xth, xtl, wt1th, wt1tl,
                                         bl1, br1, 512, xlr1, NN, 1024, INC, 8);
    k_edge1p<<<NN/4, 256, 0, stream>>>(xlr1, xlr1+512, 1024, att1, bias1, row_ptr, col, z1h, z1l);
    k_mgemm_a<<<157*2, 256, 0, stream>>>(z1h, z1l, wt2th, wt2tl,
                                         bl2, br2, 128, xlr2, NN, 256, C1, 2);
    k_edge2p<<<NN/4, 256, 0, stream>>>(xlr2, xlr2+128, 256, att2, bias2, row_ptr, col, z2h, z2l);
    // UV = z2 @ [Wd1_top | Wd1_bot] + [bd1 | 0]    (per-node factoring of the decoder)
    k_mgemm_a<<<157*2, 256, 0, stream>>>(z2h, z2l, wdth, wdtl,
                                         bd1, nullptr, 128, UV, NN, 256, 128, 2);
    k_dec5<<<2048, 256, 0, stream>>>(UV, eli, Wd2, bd2, out);
  } else {
    u16* xl1 = (u16*)wA;
    u16* xr1 = (u16*)wB;
    u16* z1  = (u16*)wC;
    float* xl2 = (float*)wA;
    float* xr2 = (float*)wB;
    float* z2  = (float*)wC;
    k_hist<<<(ETOT+255)/256, 256, 0, stream>>>(ei, cnt);
    k_scan_a<<<NB, 256, 0, stream>>>(cnt, row_ptr, bsum);
    k_scan_b<<<1, 128, 0, stream>>>(bsum, row_ptr);
    k_scan_c<<<NB, 256, 0, stream>>>(row_ptr, bsum, cnt);
    k_scatter<<<(ETOT+255)/256, 256, 0, stream>>>(ei, cnt, col);
    dim3 g1((NN+63)/64, C1/64);
    dim3 g2((NN+63)/64, C2/64);
    k_gemm<float,u16><<<g1, 256, 0, stream>>>(x, Wl1, bl1, xl1, NN, C1, INC);
    k_gemm<float,u16><<<g1, 256, 0, stream>>>(x, Wr1, br1, xr1, NN, C1, INC);
    k_edge1c<u16,u16><<<NN/4, 256, 0, stream>>>(xl1, xr1, C1, att1, bias1, row_ptr, col, z1);
    k_gemm<u16,float><<<g2, 256, 0, stream>>>(z1, Wl2, bl2, xl2, NN, C2, C1);
    k_gemm<u16,float><<<g2, 256, 0, stream>>>(z1, Wr2, br2, xr2, NN, C2, C1);
    k_edge2c<float,float><<<NN/4, 256, 0, stream>>>(xl2, xr2, C2, att2, bias2, row_ptr, col, z2);
    k_dec2<<<(ELN+63)/64, 256, 0, stream>>>(z2, eli, Wd1, bd1, Wd2, bd2, out);
  }
}